// Round 6
// baseline (267.949 us; speedup 1.0000x reference)
//
#include <hip/hip_runtime.h>

// CTC loss forward (sum reduction). Shapes fixed: T=1000, B=64, V=512, S=100.
// TWO-PASS design (R5 post-mortem: harness re-poisons 512 MB of d_ws ->
// ws_size ~512MB >> the 65.5 MB we need; and every stage added to the
// barrier-coupled producer/consumer path costs more than it saves).
//   PASS 1 (ctc_pre, 512 blocks x 256 thr, massively parallel): for each
//     (t,b,lane) gather {blank, c1[lane], c3[lane]} from logp (L3-resident),
//     fmaf+exp2, fold state masks, store compact f4{eb*m0,e1*m1,eb*m2,e3*m3}
//     -> ws, coalesced dwordx4. All scatter + transcendentals leave the
//     serial path.
//   PASS 2 (ctc_alpha2, 64 blocks x 1 wave, serial): per 8-step window:
//     issue 8x global_load_lds(16B) for chunk j+3 (1024 B/row, contiguous,
//     coalesced), 8x ds_read_b128 (conflict-free) + 8 linear-domain
//     recursion steps, counted s_waitcnt vmcnt(16) (never 0 mid-loop).
//     NO barriers, NO producer waves, NO bank conflicts, no exp2.
//     4 bufs x 8 rows x 1024 B = 32 KiB LDS. Tail waits 16 -> 8 -> 0.
//   Numerics unchanged (proven R0-R5): linear domain, 2^5/step scale, DPP
//   wave-max renorm every 2 windows; loss = -ln2*(log2(sum)+rs-5*Tin).
//   Fallbacks: ws >= 1KB -> R1 producer/consumer kernel (best verified
//   single-pass, ~67us); else log-domain single pass.

#define NEGF (-1e30f)

constexpr int CT_T  = 1000;
constexpr int CT_B  = 64;
constexpr int CT_V  = 512;
constexpr int CT_S  = 100;
constexpr int CT_Se = 201;
constexpr float LOG2E = 1.4426950408889634f;
constexpr float LN2   = 0.6931471805599453f;
constexpr float SHIFT = 5.0f;

typedef float f4 __attribute__((ext_vector_type(4)));

#if __has_builtin(__builtin_amdgcn_exp2f) && __has_builtin(__builtin_amdgcn_logf)
__device__ __forceinline__ float fexp2(float x) { return __builtin_amdgcn_exp2f(x); }
__device__ __forceinline__ float flog2(float x) { return __builtin_amdgcn_logf(x); }
__device__ __forceinline__ float frcp(float x)  { return __builtin_amdgcn_rcpf(x); }
#else
__device__ __forceinline__ float fexp2(float x) { return exp2f(x); }
__device__ __forceinline__ float flog2(float x) { return log2f(x); }
__device__ __forceinline__ float frcp(float x)  { return 1.0f / x; }
#endif

__device__ __forceinline__ float lae2_b2(float x, float y) {
    float m = fmaxf(x, y);
    float d = fminf(x, y) - m;
    return m + flog2(1.0f + fexp2(d));
}
__device__ __forceinline__ float lae3_b2(float x, float y, float z) {
    float m = fmaxf(fmaxf(x, y), z);
    float s = fexp2(x - m) + fexp2(y - m) + fexp2(z - m);
    return m + flog2(s);
}

// lane l <- lane l-1 (lane 0 <- 0): DPP wave_shr:1, VALU speed.
__device__ __forceinline__ float wave_shr1(float x) {
    return __int_as_float(__builtin_amdgcn_update_dpp(
        0, __float_as_int(x), 0x138, 0xf, 0xf, true));
}
// wave max of NON-NEGATIVE x, all-VALU DPP reduce; uniform via readlane 63.
__device__ __forceinline__ float wave_max_nonneg(float x) {
#define DPPMAX(ctrl) x = fmaxf(x, __int_as_float(__builtin_amdgcn_update_dpp( \
        0, __float_as_int(x), ctrl, 0xf, 0xf, true)))
    DPPMAX(0x111); DPPMAX(0x112); DPPMAX(0x114); DPPMAX(0x118);
    DPPMAX(0x142); DPPMAX(0x143);
#undef DPPMAX
    return __int_as_float(__builtin_amdgcn_readlane(__float_as_int(x), 63));
}

typedef const __attribute__((address_space(1))) unsigned int* as1_uint_ptr;
typedef __attribute__((address_space(3))) unsigned int* as3_uint_ptr;
__device__ __forceinline__ void gld16(const void* g, void* l) {
    __builtin_amdgcn_global_load_lds((as1_uint_ptr)g, (as3_uint_ptr)l, 16, 0, 0);
}

#define WAIT_VM(n) do { \
    asm volatile("s_waitcnt vmcnt(" #n ")" ::: "memory"); \
    __builtin_amdgcn_sched_barrier(0); } while (0)

// =================== PASS 1: parallel gather + exp2 + fold ==================
__global__ __launch_bounds__(256) void ctc_pre(
    const float* __restrict__ logp,    // (T, B, V)
    const int*   __restrict__ tgt,
    const int*   __restrict__ tgt_len,
    float*       __restrict__ wsd)     // (B, T, 64 lanes, 4) floats
{
    const int b    = blockIdx.x;
    const int slab = blockIdx.y;            // 8 slabs x 125 t
    const int wv   = threadIdx.x >> 6;
    const int lane = threadIdx.x & 63;
    const int Lt   = tgt_len[b];
    const int lim  = 2 * Lt + 1;
    const int* tg  = tgt + b * CT_S;

    const int s0 = 4 * lane, s1 = s0 + 1, s3 = s0 + 3;
    const int i1 = min((s1 - 1) >> 1, CT_S - 1);
    const int i3 = min((s3 - 1) >> 1, CT_S - 1);
    const int c1 = tg[i1];
    const int c3 = tg[i3];
    const float m0 = (s0     < lim) ? 1.f : 0.f;
    const float m1 = (s0 + 1 < lim) ? 1.f : 0.f;
    const float m2 = (s0 + 2 < lim) ? 1.f : 0.f;
    const float m3 = (s0 + 3 < lim) ? 1.f : 0.f;

    const int t0 = slab * 125;
    const int t1 = min(t0 + 125, CT_T);
    for (int t = t0 + wv; t < t1; t += 4) {
        const float* r = logp + ((size_t)t * CT_B + b) * CT_V;
        float eb = fexp2(fmaf(r[1],  LOG2E, SHIFT));   // broadcast col
        float e1 = fexp2(fmaf(r[c1], LOG2E, SHIFT));   // per-lane gather
        float e3 = fexp2(fmaf(r[c3], LOG2E, SHIFT));   // per-lane gather
        f4 v;
        v.x = eb * m0; v.y = e1 * m1; v.z = eb * m2; v.w = e3 * m3;
        *reinterpret_cast<f4*>(wsd + (((size_t)b * CT_T + t) << 8) + 4 * lane) = v;
    }
}

// =================== PASS 2: serial recursion, single wave/b ================
__global__ __launch_bounds__(64, 1) void ctc_alpha2(
    const float* __restrict__ logp,    // only for t=0 init
    const int*   __restrict__ in_len,
    const int*   __restrict__ tgt,
    const int*   __restrict__ tgt_len,
    const float* __restrict__ wsd,
    float*       __restrict__ loss_ws)
{
    __shared__ __align__(16) float ldsq[4][8][256];   // 32 KiB

    const int b    = blockIdx.x;
    const int lane = threadIdx.x;
    const int Tin  = in_len[b];
    const int Lt   = tgt_len[b];
    const int* tg  = tgt + b * CT_S;

    const int K = (Tin - 1 + 7) / 8;     // >= 63 since Tin >= 500

    const int s1 = 4 * lane + 1, s3 = 4 * lane + 3;
    const int i1 = min((s1 - 1) >> 1, CT_S - 1);
    const int i3 = min((s3 - 1) >> 1, CT_S - 1);
    const int c1 = tg[i1];
    const float sk1 = ((s1 >= 3) && (s1 < CT_Se) && (c1 != tg[max(i1 - 1, 0)])) ? 1.f : 0.f;
    const float sk3 = ((s3 >= 3) && (s3 < CT_Se) && (tg[i3] != tg[max(i3 - 1, 0)])) ? 1.f : 0.f;

    float a0 = 0.f, a1 = 0.f, a2 = 0.f, a3 = 0.f, pa3 = 0.f;
    if (lane == 0) {
        const float* r0 = logp + (size_t)b * CT_V;
        a0 = fexp2(fmaf(r0[1], LOG2E, SHIFT));
        if (Lt > 0) a1 = fexp2(fmaf(r0[c1], LOG2E, SHIFT));
    }
    float rs = 0.f;   // accumulated renorm log2-scale (wave-uniform)

    const char* src = (const char*)(wsd + ((size_t)b * CT_T << 8));

    auto iss2 = [&](int k) {
        const int tb = 1 + 8 * k;
        const int buf = k & 3;
        #pragma unroll
        for (int i = 0; i < 8; ++i) {
            const int t = min(tb + i, CT_T - 1);
            gld16(src + ((size_t)t << 10) + (size_t)lane * 16, &ldsq[buf][i][0]);
        }
    };

    auto renorm = [&]() {
        float lm = wave_max_nonneg(fmaxf(fmaxf(a0, a1), fmaxf(a2, a3)));
        if (lm > 0.f) {
            float sc = frcp(lm);
            rs += flog2(lm);
            a0 *= sc; a1 *= sc; a2 *= sc; a3 *= sc;
            pa3 = wave_shr1(a3);
        }
    };

    auto run8 = [&](int buf, int tb, bool guard) {
        unsigned base = (unsigned)(size_t)(&ldsq[buf][0][0]) + 16u * (unsigned)lane;
        f4 e[8];
        asm volatile(
            "ds_read_b128 %0, %8 offset:0\n\t"
            "ds_read_b128 %1, %8 offset:1024\n\t"
            "ds_read_b128 %2, %8 offset:2048\n\t"
            "ds_read_b128 %3, %8 offset:3072\n\t"
            "ds_read_b128 %4, %8 offset:4096\n\t"
            "ds_read_b128 %5, %8 offset:5120\n\t"
            "ds_read_b128 %6, %8 offset:6144\n\t"
            "ds_read_b128 %7, %8 offset:7168\n\t"
            "s_waitcnt lgkmcnt(0)"
            : "=&v"(e[0]), "=&v"(e[1]), "=&v"(e[2]), "=&v"(e[3]),
              "=&v"(e[4]), "=&v"(e[5]), "=&v"(e[6]), "=&v"(e[7])
            : "v"(base));
        #pragma unroll
        for (int i = 0; i < 8; ++i) {
            float n0 = (a0 + pa3) * e[i].x;
            float n1 = fmaf(sk1, pa3, a1 + a0) * e[i].y;
            float n2 = (a2 + a1) * e[i].z;
            float n3 = fmaf(sk3, a1, a3 + a2) * e[i].w;
            if (!guard || (tb + i < Tin)) { a0 = n0; a1 = n1; a2 = n2; a3 = n3; }
            pa3 = wave_shr1(a3);
        }
    };

    // prologue: zero vmcnt ledger (preamble loads), fill 3 chunks, gate chunk0
    WAIT_VM(0);
    iss2(0); iss2(1); iss2(2);
    WAIT_VM(16);                         // chunk 0 landed; 1,2 in flight

    for (int j = 0; j < K; ++j) {
        if (j + 3 < K) iss2(j + 3);      // into buf (j-1)&3, reads done @ j-1
        run8(j & 3, 1 + 8 * j, j == K - 1);
        if (j & 1) renorm();
        // gate chunk j+1 for next window; counted, never stalls long
        if (j + 3 < K)      { WAIT_VM(16); }
        else if (j + 2 < K) { WAIT_VM(8); }
        else if (j + 1 < K) { WAIT_VM(0); }
    }

    const int last = 2 * Lt;
    const int prev = max(last - 1, 0);
    const int lr = last & 3, lidx = last >> 2;
    float av = (lr == 0) ? a0 : (lr == 1) ? a1 : (lr == 2) ? a2 : a3;
    float a_last = __shfl(av, lidx);
    const int pr = prev & 3, pidx = prev >> 2;
    float pv = (pr == 0) ? a0 : (pr == 1) ? a1 : (pr == 2) ? a2 : a3;
    float a_prev = __shfl(pv, pidx);

    float sum = a_last + a_prev;
    float loss = 0.f;
    if (sum > 0.f)
        loss = -(flog2(sum) + rs - SHIFT * (float)Tin) * LN2;
    if (lane == 0) loss_ws[b] = loss;
}

// ============ Fallback 1: R1 producer/consumer (verified, ~67us) ============
__global__ __launch_bounds__(256, 1) void ctc_alpha_pc(
    const float* __restrict__ logp,
    const int*   __restrict__ in_len,
    const int*   __restrict__ tgt,
    const int*   __restrict__ tgt_len,
    float*       __restrict__ loss_ws)
{
    __shared__ float ldsr[4][8][CT_V];   // 64 KiB

    const int b    = blockIdx.x;
    const int tid  = threadIdx.x;
    const int wv   = tid >> 6;
    const int lane = tid & 63;
    const int Tin  = in_len[b];
    const int Lt   = tgt_len[b];
    const int lim  = 2 * Lt + 1;
    const int* tg  = tgt + b * CT_S;

    const int Kf = (Tin - 1) / 8;
    const int K  = (Tin - 1 + 7) / 8;

    const int s0 = 4 * lane, s1 = s0 + 1, s3 = s0 + 3;
    const int i1 = min((s1 - 1) >> 1, CT_S - 1);
    const int i3 = min((s3 - 1) >> 1, CT_S - 1);
    const int c1 = tg[i1];
    const int c3 = tg[i3];
    const float sk1 = ((s1 >= 3) && (s1 < CT_Se) && (c1 != tg[max(i1 - 1, 0)])) ? 1.f : 0.f;
    const float sk3 = ((s3 >= 3) && (s3 < CT_Se) && (c3 != tg[max(i3 - 1, 0)])) ? 1.f : 0.f;
    const float m0 = (s0     < lim) ? 1.f : 0.f;
    const float m1 = (s0 + 1 < lim) ? 1.f : 0.f;
    const float m2 = (s0 + 2 < lim) ? 1.f : 0.f;
    const float m3 = (s0 + 3 < lim) ? 1.f : 0.f;

    float a0 = 0.f, a1 = 0.f, a2 = 0.f, a3 = 0.f, pa3 = 0.f;
    if (tid == 0) {
        const float* r0 = logp + (size_t)b * CT_V;
        a0 = fexp2(fmaf(r0[1], LOG2E, SHIFT));
        if (Lt > 0) a1 = fexp2(fmaf(r0[c1], LOG2E, SHIFT));
    }
    float rs = 0.f;

    auto issue = [&](int k, int buf) {
        const int tb = 1 + 8 * k;
        #pragma unroll
        for (int i = 0; i < 8; ++i) {
            const int t = min(tb + i, CT_T - 1);
            const char* g = (const char*)(logp + ((size_t)t * CT_B + b) * CT_V)
                          + (size_t)lane * 16;
            gld16(g,        &ldsr[buf][i][0]);
            gld16(g + 1024, &ldsr[buf][i][256]);
        }
    };

    auto renorm = [&]() {
        float lm = wave_max_nonneg(fmaxf(fmaxf(a0, a1), fmaxf(a2, a3)));
        if (lm > 0.f) {
            float sc = frcp(lm);
            rs += flog2(lm);
            a0 *= sc; a1 *= sc; a2 *= sc; a3 *= sc;
            pa3 = wave_shr1(a3);
        }
    };

    auto run8 = [&](int buf, int tb, bool guard) {
        unsigned base = (unsigned)(size_t)(&ldsr[buf][0][0]);
        unsigned ab = base + 4u * 1;
        unsigned a1a = base + 4u * (unsigned)c1;
        unsigned a3a = base + 4u * (unsigned)c3;
        float g0,g1,g2,g3,g4,g5,g6,g7,g8,g9,g10,g11,
              g12,g13,g14,g15,g16,g17,g18,g19,g20,g21,g22,g23;
        asm volatile(
            "ds_read_b32 %0,  %24 offset:0\n\t"
            "ds_read_b32 %1,  %25 offset:0\n\t"
            "ds_read_b32 %2,  %26 offset:0\n\t"
            "ds_read_b32 %3,  %24 offset:2048\n\t"
            "ds_read_b32 %4,  %25 offset:2048\n\t"
            "ds_read_b32 %5,  %26 offset:2048\n\t"
            "ds_read_b32 %6,  %24 offset:4096\n\t"
            "ds_read_b32 %7,  %25 offset:4096\n\t"
            "ds_read_b32 %8,  %26 offset:4096\n\t"
            "ds_read_b32 %9,  %24 offset:6144\n\t"
            "ds_read_b32 %10, %25 offset:6144\n\t"
            "ds_read_b32 %11, %26 offset:6144\n\t"
            "ds_read_b32 %12, %24 offset:8192\n\t"
            "ds_read_b32 %13, %25 offset:8192\n\t"
            "ds_read_b32 %14, %26 offset:8192\n\t"
            "ds_read_b32 %15, %24 offset:10240\n\t"
            "ds_read_b32 %16, %25 offset:10240\n\t"
            "ds_read_b32 %17, %26 offset:10240\n\t"
            "ds_read_b32 %18, %24 offset:12288\n\t"
            "ds_read_b32 %19, %25 offset:12288\n\t"
            "ds_read_b32 %20, %26 offset:12288\n\t"
            "ds_read_b32 %21, %24 offset:14336\n\t"
            "ds_read_b32 %22, %25 offset:14336\n\t"
            "ds_read_b32 %23, %26 offset:14336\n\t"
            "s_waitcnt lgkmcnt(0)"
            : "=&v"(g0), "=&v"(g1), "=&v"(g2), "=&v"(g3), "=&v"(g4), "=&v"(g5),
              "=&v"(g6), "=&v"(g7), "=&v"(g8), "=&v"(g9), "=&v"(g10), "=&v"(g11),
              "=&v"(g12), "=&v"(g13), "=&v"(g14), "=&v"(g15), "=&v"(g16), "=&v"(g17),
              "=&v"(g18), "=&v"(g19), "=&v"(g20), "=&v"(g21), "=&v"(g22), "=&v"(g23)
            : "v"(ab), "v"(a1a), "v"(a3a));

        float eb[8], e1[8], e3[8];
        float gb[24] = {g0,g1,g2,g3,g4,g5,g6,g7,g8,g9,g10,g11,
                        g12,g13,g14,g15,g16,g17,g18,g19,g20,g21,g22,g23};
        #pragma unroll
        for (int i = 0; i < 8; ++i) {
            eb[i] = fexp2(fmaf(gb[3 * i],     LOG2E, SHIFT));
            e1[i] = fexp2(fmaf(gb[3 * i + 1], LOG2E, SHIFT));
            e3[i] = fexp2(fmaf(gb[3 * i + 2], LOG2E, SHIFT));
        }
        #pragma unroll
        for (int i = 0; i < 8; ++i) {
            float ex = eb[i] * m0, ey = e1[i] * m1;
            float ez = eb[i] * m2, ew = e3[i] * m3;
            float n0 = (a0 + pa3) * ex;
            float n1 = fmaf(sk1, pa3, a1 + a0) * ey;
            float n2 = (a2 + a1) * ez;
            float n3 = fmaf(sk3, a1, a3 + a2) * ew;
            if (!guard || (tb + i < Tin)) { a0 = n0; a1 = n1; a2 = n2; a3 = n3; }
            pa3 = wave_shr1(a3);
        }
    };

    if (wv) {
        const int p = wv - 1;
        if (p < K) issue(p, p);
        if (p == 0)
            asm volatile("s_waitcnt vmcnt(0)" ::: "memory");
    }
    __builtin_amdgcn_s_barrier();

    for (int j = 0; j < K; ++j) {
        if (wv == 0) {
            if (j < Kf) { run8(j & 3, 0, false); if (j & 1) renorm(); }
            else        run8(j & 3, 1 + 8 * j, true);
        } else {
            const int p = wv - 1;
            if ((j % 3) == p && (j + 3) < K) issue(j + 3, (j + 3) & 3);
            if (((j + 1) % 3) == p && (j + 1) < K)
                asm volatile("s_waitcnt vmcnt(0)" ::: "memory");
        }
        __builtin_amdgcn_s_barrier();
    }

    if (wv) {
        asm volatile("s_waitcnt vmcnt(0)" ::: "memory");
        return;
    }

    const int last = 2 * Lt;
    const int prev = max(last - 1, 0);
    const int lr = last & 3, lidx = last >> 2;
    float av = (lr == 0) ? a0 : (lr == 1) ? a1 : (lr == 2) ? a2 : a3;
    float a_last = __shfl(av, lidx);
    const int pr = prev & 3, pidx = prev >> 2;
    float pv = (pr == 0) ? a0 : (pr == 1) ? a1 : (pr == 2) ? a2 : a3;
    float a_prev = __shfl(pv, pidx);

    float sum = a_last + a_prev;
    float loss = 0.f;
    if (sum > 0.f)
        loss = -(flog2(sum) + rs - SHIFT * (float)Tin) * LN2;
    if (lane == 0) loss_ws[b] = loss;
}

// ---------------- Fallback 2 (log-domain single pass) ----------------
__global__ __launch_bounds__(64) void ctc_alpha_fb(
    const float* __restrict__ logp, const int* __restrict__ in_len,
    const int* __restrict__ tgt, const int* __restrict__ tgt_len,
    float* __restrict__ loss_ws)
{
    const int b = blockIdx.x, lane = threadIdx.x;
    const int Tin = in_len[b], Lt = tgt_len[b];
    const int ext_len = 2 * Lt + 1;
    const int* tg = tgt + b * CT_S;
    const int s0 = 4 * lane, s1 = s0 + 1, s3 = s0 + 3;
    const int i1 = min((s1 - 1) >> 1, CT_S - 1);
    const int i3 = min((s3 - 1) >> 1, CT_S - 1);
    const int c1 = tg[i1], c3 = tg[i3];
    const bool skip1 = (s1 >= 3) && (s1 < CT_Se) && (c1 != tg[max(i1 - 1, 0)]);
    const bool skip3 = (s3 >= 3) && (s3 < CT_Se) && (c3 != tg[max(i3 - 1, 0)]);
    const bool v0 = s0 < ext_len, v1 = s1 < ext_len;
    const bool v2 = (s0 + 2) < ext_len, v3 = s3 < ext_len;
    const float* row0 = logp + (long long)b * CT_V;
    const long long stride = (long long)CT_B * CT_V;
    float a0 = NEGF, a1 = NEGF, a2 = NEGF, a3 = NEGF;
    if (lane == 0) {
        a0 = row0[1] * LOG2E;
        if (ext_len > 1) a1 = row0[c1] * LOG2E;
    }
    float3 E0, E1, E2, E3;
    auto ld = [&](float3& e, int t) {
        int tt = min(t, CT_T - 1);
        const float* r = row0 + (long long)tt * stride;
        e.x = r[1] * LOG2E; e.y = r[c1] * LOG2E; e.z = r[c3] * LOG2E;
    };
    auto step = [&](const float3& e) {
        float pa3 = __shfl_up(a3, 1);
        if (lane == 0) pa3 = NEGF;
        float z1 = skip1 ? pa3 : NEGF;
        float z3 = skip3 ? a1 : NEGF;
        float n0 = v0 ? lae2_b2(a0, pa3)    + e.x : NEGF;
        float n1 = v1 ? lae3_b2(a1, a0, z1) + e.y : NEGF;
        float n2 = v2 ? lae2_b2(a2, a1)     + e.x : NEGF;
        float n3 = v3 ? lae3_b2(a3, a2, z3) + e.z : NEGF;
        a0 = n0; a1 = n1; a2 = n2; a3 = n3;
    };
    ld(E0, 1); ld(E1, 2); ld(E2, 3); ld(E3, 4);
    for (int t = 1; t < Tin; t += 4) {
        step(E0); ld(E0, t + 4);
        if (t + 1 < Tin) { step(E1); ld(E1, t + 5); }
        if (t + 2 < Tin) { step(E2); ld(E2, t + 6); }
        if (t + 3 < Tin) { step(E3); ld(E3, t + 7); }
    }
    const int last = 2 * Lt, prev = max(last - 1, 0);
    const int lr = last & 3, lidx = last >> 2;
    float av = (lr == 0) ? a0 : (lr == 1) ? a1 : (lr == 2) ? a2 : a3;
    float a_last = __shfl(av, lidx);
    const int pr = prev & 3, pidx = prev >> 2;
    float pv = (pr == 0) ? a0 : (pr == 1) ? a1 : (pr == 2) ? a2 : a3;
    float a_prev = __shfl(pv, pidx);
    float loglik = lae2_b2(a_last, a_prev) * LN2;
    float loss = (loglik < 0.5f * NEGF) ? 0.0f : -loglik;
    if (lane == 0) loss_ws[b] = loss;
}

__global__ __launch_bounds__(64) void ctc_sum(const float* __restrict__ loss_ws,
                                              float* __restrict__ out)
{
    float v = loss_ws[threadIdx.x];
    #pragma unroll
    for (int o = 32; o > 0; o >>= 1) v += __shfl_down(v, o);
    if (threadIdx.x == 0) out[0] = v;
}

extern "C" void kernel_launch(void* const* d_in, const int* in_sizes, int n_in,
                              void* d_out, int out_size, void* d_ws, size_t ws_size,
                              hipStream_t stream) {
    const float* logp    = (const float*)d_in[0];
    const int*   in_len  = (const int*)d_in[1];
    const int*   tgt     = (const int*)d_in[2];
    const int*   tgt_len = (const int*)d_in[3];
    float* out = (float*)d_out;
    float* loss_ws = (float*)d_ws;               // 256 B
    float* wsd     = loss_ws + 256;              // pass-1 data, 1 KiB offset

    const size_t need = 1024ull + (size_t)CT_B * CT_T * 256 * 4;  // 65.54 MB

    if (ws_size >= need) {
        hipLaunchKernelGGL(ctc_pre, dim3(CT_B, 8), dim3(256), 0, stream,
                           logp, tgt, tgt_len, wsd);
        hipLaunchKernelGGL(ctc_alpha2, dim3(CT_B), dim3(64), 0, stream,
                           logp, in_len, tgt, tgt_len, wsd, loss_ws);
    } else if (ws_size >= 1024) {
        hipLaunchKernelGGL(ctc_alpha_pc, dim3(CT_B), dim3(256), 0, stream,
                           logp, in_len, tgt, tgt_len, loss_ws);
    } else {
        hipLaunchKernelGGL(ctc_alpha_fb, dim3(CT_B), dim3(64), 0, stream,
                           logp, in_len, tgt, tgt_len, loss_ws);
    }
    hipLaunchKernelGGL(ctc_sum, dim3(1), dim3(64), 0, stream, loss_ws, out);
}

// Round 7
// 202.746 us; speedup vs baseline: 1.3216x; 1.3216x over previous
//
#include <hip/hip_runtime.h>

// CTC loss forward (sum reduction). Shapes fixed: T=1000, B=64, V=512, S=100.
// PING-PONG CONSUMERS + COMPACT DMA: one block (4 waves) per batch element b.
//   Session ledger: R1 (producers DMA full rows, single consumer) = best
//   (~67us kernel). Consumer window = gather-wait + prep-issue + recursion +
//   barrier. Prep (gather+exp2) is alpha-independent -> move it off the
//   serial path WITHOUT the R2/R5 coupled-handoff tax:
//   - Waves 0,1 PING-PONG: wave w recurses turns i with (i&1)==w (16 steps
//     from 64 pre-computed emission regs ex/ey/ez/ew[16]); during its off
//     turns it preps its OWN next turn's regs (conflict-free LDS reads +
//     exp2). Alpha handoff between waves: 1x ds_write_b128 + ds_read_b128
//     (+rs scalar) per turn, barrier-separated, single slot.
//   - Waves 2,3 PRODUCERS: compact staging via global_load_lds size=4 with
//     PER-LANE global src (lane l reads logp[t,b,c1[l]]) and contiguous LDS
//     dst -> per row 3x256B sections {c1,c3,blank} = 768B (vs 2KB full row).
//     8 bufs x 8 rows x 768B = 48KB -> pair issued 2 turns ahead of prep
//     (~1400cyc >= HBM latency). Producer p owns turn parity p: issues pair
//     (2i+6,2i+7) on its turns, gates (vmcnt(0), own-wave ledger) on the
//     following turn before the barrier.
//   - Sync: raw s_barrier per turn (2 + NT total). No consumer vmcnt ever.
//   - Numerics IDENTICAL to R0-R6 (passed): linear domain, 2^5/step scale,
//     wave-max renorm every 16 steps; loss = -ln2*(log2(sum)+rs-5*Tin).
//     (m1/m3 folded into exp2 shift: m=0 -> arg -1000 -> exp2=+0 == e*0.)

#define NEGF (-1e30f)

constexpr int CT_T  = 1000;
constexpr int CT_B  = 64;
constexpr int CT_V  = 512;
constexpr int CT_S  = 100;
constexpr int CT_Se = 201;
constexpr float LOG2E = 1.4426950408889634f;
constexpr float LN2   = 0.6931471805599453f;
constexpr float SHIFT = 5.0f;

typedef float f4 __attribute__((ext_vector_type(4)));

#if __has_builtin(__builtin_amdgcn_exp2f) && __has_builtin(__builtin_amdgcn_logf)
__device__ __forceinline__ float fexp2(float x) { return __builtin_amdgcn_exp2f(x); }
__device__ __forceinline__ float flog2(float x) { return __builtin_amdgcn_logf(x); }
__device__ __forceinline__ float frcp(float x)  { return __builtin_amdgcn_rcpf(x); }
#else
__device__ __forceinline__ float fexp2(float x) { return exp2f(x); }
__device__ __forceinline__ float flog2(float x) { return log2f(x); }
__device__ __forceinline__ float frcp(float x)  { return 1.0f / x; }
#endif

__device__ __forceinline__ float lae2_b2(float x, float y) {
    float m = fmaxf(x, y);
    float d = fminf(x, y) - m;
    return m + flog2(1.0f + fexp2(d));
}
__device__ __forceinline__ float lae3_b2(float x, float y, float z) {
    float m = fmaxf(fmaxf(x, y), z);
    float s = fexp2(x - m) + fexp2(y - m) + fexp2(z - m);
    return m + flog2(s);
}

// lane l <- lane l-1 (lane 0 <- 0): DPP wave_shr:1, VALU speed.
__device__ __forceinline__ float wave_shr1(float x) {
    return __int_as_float(__builtin_amdgcn_update_dpp(
        0, __float_as_int(x), 0x138, 0xf, 0xf, true));
}
// wave max of NON-NEGATIVE x, all-VALU DPP reduce; uniform via readlane 63.
__device__ __forceinline__ float wave_max_nonneg(float x) {
#define DPPMAX(ctrl) x = fmaxf(x, __int_as_float(__builtin_amdgcn_update_dpp( \
        0, __float_as_int(x), ctrl, 0xf, 0xf, true)))
    DPPMAX(0x111); DPPMAX(0x112); DPPMAX(0x114); DPPMAX(0x118);
    DPPMAX(0x142); DPPMAX(0x143);
#undef DPPMAX
    return __int_as_float(__builtin_amdgcn_readlane(__float_as_int(x), 63));
}

typedef const __attribute__((address_space(1))) unsigned int* as1_uint_ptr;
typedef __attribute__((address_space(3))) unsigned int* as3_uint_ptr;
__device__ __forceinline__ void gld16(const void* g, void* l) {
    __builtin_amdgcn_global_load_lds((as1_uint_ptr)g, (as3_uint_ptr)l, 16, 0, 0);
}
// size=4: per-lane scattered global src, LDS dst = base + lane*4 (contiguous)
__device__ __forceinline__ void gld4(const void* g, void* l) {
    __builtin_amdgcn_global_load_lds((as1_uint_ptr)g, (as3_uint_ptr)l, 4, 0, 0);
}

#define WAIT_VM0() do { \
    asm volatile("s_waitcnt vmcnt(0)" ::: "memory"); \
    __builtin_amdgcn_sched_barrier(0); } while (0)
#define DRAIN_LGKM() asm volatile("s_waitcnt lgkmcnt(0)" ::: "memory")

// ---------------- ping-pong fused recursion ----------------
__global__ __launch_bounds__(256, 1) void ctc_alpha_pp(
    const float* __restrict__ logp,    // (T, B, V)
    const int*   __restrict__ in_len,
    const int*   __restrict__ tgt,
    const int*   __restrict__ tgt_len,
    float*       __restrict__ loss_ws)
{
    // stage[buf][row][0:64]=c1 vals, [64:128]=c3 vals, [128:192]=blank copies
    __shared__ __align__(16) float stage[8][8][192];   // 48 KiB
    __shared__ __align__(16) float hand[272];          // alpha f4/lane + rs

    const int b    = blockIdx.x;
    const int tid  = threadIdx.x;
    const int wv   = tid >> 6;           // 0,1 ping-pong; 2,3 producers
    const int lane = tid & 63;
    const int Tin  = in_len[b];
    const int Lt   = tgt_len[b];
    const int lim  = 2 * Lt + 1;
    const int* tg  = tgt + b * CT_S;

    const int K  = (Tin - 1 + 7) / 8;    // chunks (8 steps each), >= 63
    const int NT = (Tin - 1 + 15) / 16;  // turns (16 steps each), >= 32

    const int s0 = 4 * lane, s1 = s0 + 1, s3 = s0 + 3;
    const int i1 = min((s1 - 1) >> 1, CT_S - 1);
    const int i3 = min((s3 - 1) >> 1, CT_S - 1);
    const int c1 = tg[i1];
    const int c3 = tg[i3];
    const float sk1 = ((s1 >= 3) && (s1 < CT_Se) && (c1 != tg[max(i1 - 1, 0)])) ? 1.f : 0.f;
    const float sk3 = ((s3 >= 3) && (s3 < CT_Se) && (c3 != tg[max(i3 - 1, 0)])) ? 1.f : 0.f;
    const float m0 = (s0     < lim) ? 1.f : 0.f;
    const float m2 = (s0 + 2 < lim) ? 1.f : 0.f;
    const float Sy = (s0 + 1 < lim) ? SHIFT : -1000.f;   // m1 folded into exp2
    const float Sw = (s0 + 3 < lim) ? SHIFT : -1000.f;   // m3 folded into exp2

    float a0 = 0.f, a1 = 0.f, a2 = 0.f, a3 = 0.f, pa3 = 0.f;
    if (tid == 0) {
        const float* r0 = logp + (size_t)b * CT_V;
        a0 = fexp2(fmaf(r0[1], LOG2E, SHIFT));
        if (Lt > 0) a1 = fexp2(fmaf(r0[c1], LOG2E, SHIFT));
    }
    float rs = 0.f;

    // emission registers for ONE 16-step turn (per ping-pong wave)
    float ex[16], ey[16], ez[16], ew[16];

    // ---- producer: compact-stage chunk c (8 rows x 3 sections)
    auto issue = [&](int c) {
        if (c >= K) return;
        const int buf = c & 7, tb = 1 + 8 * c;
        #pragma unroll
        for (int i = 0; i < 8; ++i) {
            const int t = min(tb + i, CT_T - 1);
            const float* r = logp + ((size_t)t * CT_B + b) * CT_V;
            gld4(r + c1, &stage[buf][i][0]);     // per-lane scatter -> 256B
            gld4(r + c3, &stage[buf][i][64]);
            gld4(r + 1,  &stage[buf][i][128]);   // uniform src (blank)
        }
    };

    // ---- prep: read 24 staged values of chunk c (one asm batch, wait inside)
    auto read24 = [&](int c, float (&g)[24]) {
        unsigned base = (unsigned)(size_t)(&stage[c & 7][0][0]) + 4u * (unsigned)lane;
        asm volatile(
            "ds_read_b32 %0,  %24 offset:0\n\t"
            "ds_read_b32 %1,  %24 offset:256\n\t"
            "ds_read_b32 %2,  %24 offset:512\n\t"
            "ds_read_b32 %3,  %24 offset:768\n\t"
            "ds_read_b32 %4,  %24 offset:1024\n\t"
            "ds_read_b32 %5,  %24 offset:1280\n\t"
            "ds_read_b32 %6,  %24 offset:1536\n\t"
            "ds_read_b32 %7,  %24 offset:1792\n\t"
            "ds_read_b32 %8,  %24 offset:2048\n\t"
            "ds_read_b32 %9,  %24 offset:2304\n\t"
            "ds_read_b32 %10, %24 offset:2560\n\t"
            "ds_read_b32 %11, %24 offset:2816\n\t"
            "ds_read_b32 %12, %24 offset:3072\n\t"
            "ds_read_b32 %13, %24 offset:3328\n\t"
            "ds_read_b32 %14, %24 offset:3584\n\t"
            "ds_read_b32 %15, %24 offset:3840\n\t"
            "ds_read_b32 %16, %24 offset:4096\n\t"
            "ds_read_b32 %17, %24 offset:4352\n\t"
            "ds_read_b32 %18, %24 offset:4608\n\t"
            "ds_read_b32 %19, %24 offset:4864\n\t"
            "ds_read_b32 %20, %24 offset:5120\n\t"
            "ds_read_b32 %21, %24 offset:5376\n\t"
            "ds_read_b32 %22, %24 offset:5632\n\t"
            "ds_read_b32 %23, %24 offset:5888\n\t"
            "s_waitcnt lgkmcnt(0)"
            : "=&v"(g[0]), "=&v"(g[1]), "=&v"(g[2]), "=&v"(g[3]), "=&v"(g[4]),
              "=&v"(g[5]), "=&v"(g[6]), "=&v"(g[7]), "=&v"(g[8]), "=&v"(g[9]),
              "=&v"(g[10]), "=&v"(g[11]), "=&v"(g[12]), "=&v"(g[13]),
              "=&v"(g[14]), "=&v"(g[15]), "=&v"(g[16]), "=&v"(g[17]),
              "=&v"(g[18]), "=&v"(g[19]), "=&v"(g[20]), "=&v"(g[21]),
              "=&v"(g[22]), "=&v"(g[23])
            : "v"(base));
        __builtin_amdgcn_sched_barrier(0);
    };

    // ---- prep chunks (c0, c0+1) -> emission regs for one 16-step turn
    auto prep2 = [&](int c0) {
        float gA[24], gB[24];
        read24(c0, gA);
        read24(c0 + 1, gB);
        #pragma unroll
        for (int s = 0; s < 16; ++s) {
            const float* g = (s < 8) ? &gA[3 * s] : &gB[3 * (s - 8)];
            float e1 = fexp2(fmaf(g[0], LOG2E, Sy));
            float e3 = fexp2(fmaf(g[1], LOG2E, Sw));
            float eb = fexp2(fmaf(g[2], LOG2E, SHIFT));
            ex[s] = eb * m0; ey[s] = e1; ez[s] = eb * m2; ew[s] = e3;
        }
    };

    auto renorm = [&]() {
        float lm = wave_max_nonneg(fmaxf(fmaxf(a0, a1), fmaxf(a2, a3)));
        if (lm > 0.f) {
            float sc = frcp(lm);
            rs += flog2(lm);
            a0 *= sc; a1 *= sc; a2 *= sc; a3 *= sc;
            pa3 = wave_shr1(a3);
        }
    };

    // ---- one 16-step recursion turn from emission regs (pure VALU + DPP)
    auto recurse = [&](int i) {
        if (i > 0) {                     // alpha handoff in
            f4 h = *reinterpret_cast<f4*>(&hand[4 * lane]);
            a0 = h.x; a1 = h.y; a2 = h.z; a3 = h.w;
            rs = hand[256];
            pa3 = wave_shr1(a3);
        }
        const int tb = 1 + 16 * i;
        const bool guard = (16 * i + 16 > Tin - 1);
        #pragma unroll
        for (int s = 0; s < 16; ++s) {
            float n0 = (a0 + pa3) * ex[s];
            float n1 = fmaf(sk1, pa3, a1 + a0) * ey[s];
            float n2 = (a2 + a1) * ez[s];
            float n3 = fmaf(sk3, a1, a3 + a2) * ew[s];
            if (!guard || (tb + s < Tin)) { a0 = n0; a1 = n1; a2 = n2; a3 = n3; }
            pa3 = wave_shr1(a3);
        }
        renorm();
        f4 h; h.x = a0; h.y = a1; h.z = a2; h.w = a3;   // alpha handoff out
        *reinterpret_cast<f4*>(&hand[4 * lane]) = h;
        if (lane == 0) hand[256] = rs;
        DRAIN_LGKM();
    };

    // ---- prologue: producers pre-stage chunks 0..5; gate 0..3 now
    if (wv == 2) { WAIT_VM0(); issue(0); issue(1); issue(2); issue(3); WAIT_VM0(); }
    else if (wv == 3) { WAIT_VM0(); issue(4); issue(5); }
    __builtin_amdgcn_s_barrier();        // barrier0: chunks 0..3 resident
    if (wv == 0) prep2(0);               // w0's turn-0 emission regs
    __builtin_amdgcn_s_barrier();        // barrier0b: turn 0 starts

    // ---- turn loop: barrier-separated 16-step turns
    for (int i = 0; i < NT; ++i) {
        if (wv < 2) {
            if ((i & 1) == wv)      recurse(i);
            else if (i + 1 < NT)    prep2(2 * i + 2);   // own next turn
        } else {
            const int p = wv - 2;
            if ((i & 1) == p) { issue(2 * i + 6); issue(2 * i + 7); }
            else              { WAIT_VM0(); }   // gate pair issued last turn
        }
        __builtin_amdgcn_s_barrier();
    }

    if (wv >= 2) {                       // producers: drain & exit
        asm volatile("s_waitcnt vmcnt(0)" ::: "memory");
        return;
    }
    if (wv != ((NT - 1) & 1)) return;    // final alpha lives in the other wave

    // ---- epilogue (final recursion wave holds alpha + rs)
    const int last = 2 * Lt;
    const int prev = max(last - 1, 0);
    const int lr = last & 3, lidx = last >> 2;
    float av = (lr == 0) ? a0 : (lr == 1) ? a1 : (lr == 2) ? a2 : a3;
    float a_last = __shfl(av, lidx);
    const int pr = prev & 3, pidx = prev >> 2;
    float pv = (pr == 0) ? a0 : (pr == 1) ? a1 : (pr == 2) ? a2 : a3;
    float a_prev = __shfl(pv, pidx);

    float sum = a_last + a_prev;
    float loss = 0.f;
    if (sum > 0.f)
        loss = -(flog2(sum) + rs - SHIFT * (float)Tin) * LN2;
    if (lane == 0) loss_ws[b] = loss;
}

// ---------------- Fallback (log-domain single pass) ----------------
__global__ __launch_bounds__(64) void ctc_alpha_fb(
    const float* __restrict__ logp, const int* __restrict__ in_len,
    const int* __restrict__ tgt, const int* __restrict__ tgt_len,
    float* __restrict__ loss_ws)
{
    const int b = blockIdx.x, lane = threadIdx.x;
    const int Tin = in_len[b], Lt = tgt_len[b];
    const int ext_len = 2 * Lt + 1;
    const int* tg = tgt + b * CT_S;
    const int s0 = 4 * lane, s1 = s0 + 1, s3 = s0 + 3;
    const int i1 = min((s1 - 1) >> 1, CT_S - 1);
    const int i3 = min((s3 - 1) >> 1, CT_S - 1);
    const int c1 = tg[i1], c3 = tg[i3];
    const bool skip1 = (s1 >= 3) && (s1 < CT_Se) && (c1 != tg[max(i1 - 1, 0)]);
    const bool skip3 = (s3 >= 3) && (s3 < CT_Se) && (c3 != tg[max(i3 - 1, 0)]);
    const bool v0 = s0 < ext_len, v1 = s1 < ext_len;
    const bool v2 = (s0 + 2) < ext_len, v3 = s3 < ext_len;
    const float* row0 = logp + (long long)b * CT_V;
    const long long stride = (long long)CT_B * CT_V;
    float a0 = NEGF, a1 = NEGF, a2 = NEGF, a3 = NEGF;
    if (lane == 0) {
        a0 = row0[1] * LOG2E;
        if (ext_len > 1) a1 = row0[c1] * LOG2E;
    }
    float3 E0, E1, E2, E3;
    auto ld = [&](float3& e, int t) {
        int tt = min(t, CT_T - 1);
        const float* r = row0 + (long long)tt * stride;
        e.x = r[1] * LOG2E; e.y = r[c1] * LOG2E; e.z = r[c3] * LOG2E;
    };
    auto step = [&](const float3& e) {
        float pa3 = __shfl_up(a3, 1);
        if (lane == 0) pa3 = NEGF;
        float z1 = skip1 ? pa3 : NEGF;
        float z3 = skip3 ? a1 : NEGF;
        float n0 = v0 ? lae2_b2(a0, pa3)    + e.x : NEGF;
        float n1 = v1 ? lae3_b2(a1, a0, z1) + e.y : NEGF;
        float n2 = v2 ? lae2_b2(a2, a1)     + e.x : NEGF;
        float n3 = v3 ? lae3_b2(a3, a2, z3) + e.z : NEGF;
        a0 = n0; a1 = n1; a2 = n2; a3 = n3;
    };
    ld(E0, 1); ld(E1, 2); ld(E2, 3); ld(E3, 4);
    for (int t = 1; t < Tin; t += 4) {
        step(E0); ld(E0, t + 4);
        if (t + 1 < Tin) { step(E1); ld(E1, t + 5); }
        if (t + 2 < Tin) { step(E2); ld(E2, t + 6); }
        if (t + 3 < Tin) { step(E3); ld(E3, t + 7); }
    }
    const int last = 2 * Lt, prev = max(last - 1, 0);
    const int lr = last & 3, lidx = last >> 2;
    float av = (lr == 0) ? a0 : (lr == 1) ? a1 : (lr == 2) ? a2 : a3;
    float a_last = __shfl(av, lidx);
    const int pr = prev & 3, pidx = prev >> 2;
    float pv = (pr == 0) ? a0 : (pr == 1) ? a1 : (pr == 2) ? a2 : a3;
    float a_prev = __shfl(pv, pidx);
    float loglik = lae2_b2(a_last, a_prev) * LN2;
    float loss = (loglik < 0.5f * NEGF) ? 0.0f : -loglik;
    if (lane == 0) loss_ws[b] = loss;
}

__global__ __launch_bounds__(64) void ctc_sum(const float* __restrict__ loss_ws,
                                              float* __restrict__ out)
{
    float v = loss_ws[threadIdx.x];
    #pragma unroll
    for (int o = 32; o > 0; o >>= 1) v += __shfl_down(v, o);
    if (threadIdx.x == 0) out[0] = v;
}

extern "C" void kernel_launch(void* const* d_in, const int* in_sizes, int n_in,
                              void* d_out, int out_size, void* d_ws, size_t ws_size,
                              hipStream_t stream) {
    const float* logp    = (const float*)d_in[0];
    const int*   in_len  = (const int*)d_in[1];
    const int*   tgt     = (const int*)d_in[2];
    const int*   tgt_len = (const int*)d_in[3];
    float* out = (float*)d_out;
    float* loss_ws = (float*)d_ws;   // needs only 256 B

    if (ws_size >= 256 * sizeof(float)) {
        hipLaunchKernelGGL(ctc_alpha_pp, dim3(CT_B), dim3(256), 0, stream,
                           logp, in_len, tgt, tgt_len, loss_ws);
    } else {
        hipLaunchKernelGGL(ctc_alpha_fb, dim3(CT_B), dim3(64), 0, stream,
                           logp, in_len, tgt, tgt_len, loss_ws);
    }
    hipLaunchKernelGGL(ctc_sum, dim3(1), dim3(64), 0, stream, loss_ws, out);
}